// Round 5
// baseline (260.072 us; speedup 1.0000x reference)
//
#include <hip/hip_runtime.h>
#include <hip/hip_bf16.h>

// B=128, T=1024, D=1024, fp32.
// scores = (z_rppg@Wq@Wk^T) . z_eeg  -- K never materialized.
// ONE kernel, 256 blocks x 512 threads (<=1 block/CU -> all blocks resident),
// manual grid barrier (fence + atomicAdd + spin, state in d_ws, re-zeroed by
// hipMemsetAsync each call). Phases:
//   P1 Qpart  = split-k(4) partials of z_rppg @ Wq
//   P2 Qkpart = split-k(4) partials of (sum Qpart) @ Wk^T
//   P3 flash pass over z_eeg -> Npart[bid,:], Zpart[bid]   (2 half-T blocks / b)
//   P4 A = sum Npart / sum Zpart
//   P5 split-k(16) partials: fpart = concat(A,z)@Wf_w, mpart = A@Wm_w
//   P6 h = relu(z_rppg + (m+Wm_b)*sigmoid(f+Wf_b+bf))

#define BB   128
#define TT   1024
#define DD   1024
#define NB   256
#define NTH  512
#define QS   4
#define KSE  16

union SharedU {
  struct { float Xs[16][64]; float Ws[128][65]; } g;   // 37.3 KB (P1/P2)
  struct { float4 sacc[8][256]; float szw[8]; } a;     // 32.0 KB (P3)
  struct { float Cst[32][132]; float Wst[32][68]; } e; // 25.6 KB (P5)
};

__device__ __forceinline__ void gsync(int* cnt, int* rel, int gen) {
  __syncthreads();
  if (threadIdx.x == 0) {
    __threadfence();
    int old = __hip_atomic_fetch_add(cnt, 1, __ATOMIC_RELAXED, __HIP_MEMORY_SCOPE_AGENT);
    if (old == NB * gen - 1) {
      __hip_atomic_store(rel, gen, __ATOMIC_RELAXED, __HIP_MEMORY_SCOPE_AGENT);
    } else {
      while (__hip_atomic_load(rel, __ATOMIC_RELAXED, __HIP_MEMORY_SCOPE_AGENT) < gen) {
        __builtin_amdgcn_s_sleep(2);
      }
    }
    __threadfence();
  }
  __syncthreads();
}

__device__ __forceinline__ void outer_acc(float4 acc[4], const float4 a, const float4 w) {
  acc[0].x = fmaf(a.x, w.x, acc[0].x); acc[0].y = fmaf(a.x, w.y, acc[0].y);
  acc[0].z = fmaf(a.x, w.z, acc[0].z); acc[0].w = fmaf(a.x, w.w, acc[0].w);
  acc[1].x = fmaf(a.y, w.x, acc[1].x); acc[1].y = fmaf(a.y, w.y, acc[1].y);
  acc[1].z = fmaf(a.y, w.z, acc[1].z); acc[1].w = fmaf(a.y, w.w, acc[1].w);
  acc[2].x = fmaf(a.z, w.x, acc[2].x); acc[2].y = fmaf(a.z, w.y, acc[2].y);
  acc[2].z = fmaf(a.z, w.z, acc[2].z); acc[2].w = fmaf(a.z, w.w, acc[2].w);
  acc[3].x = fmaf(a.w, w.x, acc[3].x); acc[3].y = fmaf(a.w, w.y, acc[3].y);
  acc[3].z = fmaf(a.w, w.z, acc[3].z); acc[3].w = fmaf(a.w, w.w, acc[3].w);
}

__global__ __launch_bounds__(NTH, 2) void k_fused(
    const float* __restrict__ z_eeg, const float* __restrict__ z_rppg,
    const float* __restrict__ Wq, const float* __restrict__ Wk,
    const float* __restrict__ Wm_w, const float* __restrict__ Wm_b,
    const float* __restrict__ Wf_w, const float* __restrict__ Wf_b,
    const float* __restrict__ bfp, float* __restrict__ out,
    float* __restrict__ Qpart, float* __restrict__ Qkpart,
    float* __restrict__ Npart, float* __restrict__ Zpart,
    float* __restrict__ A, float* __restrict__ fpart, float* __restrict__ mpart,
    int* cnt, int* rel) {
  __shared__ SharedU sh;
  const int t = threadIdx.x;
  const int bid = blockIdx.x;  // 0..255

  // ===== P1: Qpart[p,b,e] = partial z_rppg @ Wq =====
  {
    const int ebase = (bid & 7) * 128;
    const int bbase = ((bid >> 3) & 7) * 16;
    const int p = bid >> 6;  // 0..3
    const int e = ebase + (t & 127);
    const int bg = t >> 7;   // 0..3
    float acc[4] = {0.f, 0.f, 0.f, 0.f};
    const int kend = p * 256 + 256;
    for (int k0 = p * 256; k0 < kend; k0 += 64) {
#pragma unroll
      for (int j = 0; j < 2; ++j) {
        int i = t + NTH * j;  // 0..1023
        sh.g.Xs[i >> 6][i & 63] = z_rppg[(size_t)(bbase + (i >> 6)) * DD + k0 + (i & 63)];
      }
      __syncthreads();
#pragma unroll 16
      for (int kk = 0; kk < 64; ++kk) {
        float w = Wq[(size_t)(k0 + kk) * DD + e];
#pragma unroll
        for (int j = 0; j < 4; ++j) acc[j] = fmaf(sh.g.Xs[bg + 4 * j][kk], w, acc[j]);
      }
      __syncthreads();
    }
#pragma unroll
    for (int j = 0; j < 4; ++j)
      Qpart[(size_t)p * BB * DD + (size_t)(bbase + bg + 4 * j) * DD + e] = acc[j];
  }
  gsync(cnt, rel, 1);

  // ===== P2: Qkpart[p,b,d] = partial (sum Qpart) @ Wk^T =====
  {
    const int dbase = (bid & 7) * 128;
    const int bbase = ((bid >> 3) & 7) * 16;
    const int p = bid >> 6;
    const int dl = t & 127;
    const int bg = t >> 7;
    float acc[4] = {0.f, 0.f, 0.f, 0.f};
    const int kend = p * 256 + 256;
    for (int k0 = p * 256; k0 < kend; k0 += 64) {
#pragma unroll
      for (int j = 0; j < 2; ++j) {
        int i = t + NTH * j;
        const size_t base = (size_t)(bbase + (i >> 6)) * DD + k0 + (i & 63);
        sh.g.Xs[i >> 6][i & 63] = Qpart[base] + Qpart[base + (size_t)BB * DD] +
                                  Qpart[base + 2 * (size_t)BB * DD] +
                                  Qpart[base + 3 * (size_t)BB * DD];
      }
#pragma unroll
      for (int j = 0; j < 16; ++j) {
        int i = t + NTH * j;  // 0..8191
        sh.g.Ws[i >> 6][i & 63] = Wk[(size_t)(dbase + (i >> 6)) * DD + k0 + (i & 63)];
      }
      __syncthreads();
#pragma unroll 8
      for (int kk = 0; kk < 64; ++kk) {
        float w = sh.g.Ws[dl][kk];
#pragma unroll
        for (int j = 0; j < 4; ++j) acc[j] = fmaf(sh.g.Xs[bg + 4 * j][kk], w, acc[j]);
      }
      __syncthreads();
    }
#pragma unroll
    for (int j = 0; j < 4; ++j)
      Qkpart[(size_t)p * BB * DD + (size_t)(bbase + bg + 4 * j) * DD + dbase + dl] = acc[j];
  }
  gsync(cnt, rel, 2);

  // ===== P3: flash pass over z_eeg; block = (b, half-of-T) =====
  {
    const int b = bid >> 1;
    const int th = bid & 1;
    const int lane = t & 63;
    const int w = t >> 6;  // 0..7

    float4 qk4[4];
#pragma unroll
    for (int q = 0; q < 4; ++q) {
      float4 a = ((const float4*)(Qkpart + (size_t)b * DD))[q * 64 + lane];
#pragma unroll
      for (int pp = 1; pp < QS; ++pp) {
        float4 s = ((const float4*)(Qkpart + ((size_t)pp * BB + b) * DD))[q * 64 + lane];
        a.x += s.x; a.y += s.y; a.z += s.z; a.w += s.w;
      }
      a.x *= 0.03125f; a.y *= 0.03125f; a.z *= 0.03125f; a.w *= 0.03125f;
      qk4[q] = a;
    }

    float4 acc[4] = {};
    float zsum = 0.f;
    const float4* zb = (const float4*)(z_eeg + (size_t)b * TT * DD);
    const int rbase = th * 512 + w * 4;

    for (int i = 0; i < 16; ++i) {
      const int r0 = rbase + i * 32;
      const float4* p0 = zb + (size_t)(r0 + 0) * 256;
      const float4* p1 = zb + (size_t)(r0 + 1) * 256;
      const float4* p2 = zb + (size_t)(r0 + 2) * 256;
      const float4* p3 = zb + (size_t)(r0 + 3) * 256;
      float4 z0[4], z1[4], z2[4], z3[4];
#pragma unroll
      for (int q = 0; q < 4; ++q) z0[q] = p0[q * 64 + lane];
#pragma unroll
      for (int q = 0; q < 4; ++q) z1[q] = p1[q * 64 + lane];
#pragma unroll
      for (int q = 0; q < 4; ++q) z2[q] = p2[q * 64 + lane];
#pragma unroll
      for (int q = 0; q < 4; ++q) z3[q] = p3[q * 64 + lane];
      float d0 = 0.f, d1 = 0.f, d2 = 0.f, d3 = 0.f;
#pragma unroll
      for (int q = 0; q < 4; ++q) {
        d0 += z0[q].x * qk4[q].x + z0[q].y * qk4[q].y + z0[q].z * qk4[q].z + z0[q].w * qk4[q].w;
        d1 += z1[q].x * qk4[q].x + z1[q].y * qk4[q].y + z1[q].z * qk4[q].z + z1[q].w * qk4[q].w;
        d2 += z2[q].x * qk4[q].x + z2[q].y * qk4[q].y + z2[q].z * qk4[q].z + z2[q].w * qk4[q].w;
        d3 += z3[q].x * qk4[q].x + z3[q].y * qk4[q].y + z3[q].z * qk4[q].z + z3[q].w * qk4[q].w;
      }
#pragma unroll
      for (int off = 32; off >= 1; off >>= 1) {
        d0 += __shfl_xor(d0, off);
        d1 += __shfl_xor(d1, off);
        d2 += __shfl_xor(d2, off);
        d3 += __shfl_xor(d3, off);
      }
      const float e0 = __expf(d0);
      const float e1 = __expf(d1);
      const float e2 = __expf(d2);
      const float e3 = __expf(d3);
      zsum += e0 + e1 + e2 + e3;
#pragma unroll
      for (int q = 0; q < 4; ++q) {
        acc[q].x = fmaf(e0, z0[q].x, acc[q].x); acc[q].y = fmaf(e0, z0[q].y, acc[q].y);
        acc[q].z = fmaf(e0, z0[q].z, acc[q].z); acc[q].w = fmaf(e0, z0[q].w, acc[q].w);
        acc[q].x = fmaf(e1, z1[q].x, acc[q].x); acc[q].y = fmaf(e1, z1[q].y, acc[q].y);
        acc[q].z = fmaf(e1, z1[q].z, acc[q].z); acc[q].w = fmaf(e1, z1[q].w, acc[q].w);
        acc[q].x = fmaf(e2, z2[q].x, acc[q].x); acc[q].y = fmaf(e2, z2[q].y, acc[q].y);
        acc[q].z = fmaf(e2, z2[q].z, acc[q].z); acc[q].w = fmaf(e2, z2[q].w, acc[q].w);
        acc[q].x = fmaf(e3, z3[q].x, acc[q].x); acc[q].y = fmaf(e3, z3[q].y, acc[q].y);
        acc[q].z = fmaf(e3, z3[q].z, acc[q].z); acc[q].w = fmaf(e3, z3[q].w, acc[q].w);
      }
    }

#pragma unroll
    for (int q = 0; q < 4; ++q) sh.a.sacc[w][q * 64 + lane] = acc[q];
    if (lane == 0) sh.a.szw[w] = zsum;
    __syncthreads();
    if (t < 256) {
      float4 s = sh.a.sacc[0][t];
#pragma unroll
      for (int ww = 1; ww < 8; ++ww) {
        float4 v = sh.a.sacc[ww][t];
        s.x += v.x; s.y += v.y; s.z += v.z; s.w += v.w;
      }
      ((float4*)(Npart + (size_t)bid * DD))[t] = s;
      if (t == 0) {
        float z = 0.f;
#pragma unroll
        for (int ww = 0; ww < 8; ++ww) z += sh.a.szw[ww];
        Zpart[bid] = z;
      }
    }
  }
  gsync(cnt, rel, 3);

  // ===== P4: A = (N0+N1)/(Z0+Z1) =====
  {
    const int idx = bid * NTH + t;  // 0..131071
    const int b = idx >> 10;
    const int d = idx & 1023;
    float n = Npart[(size_t)(2 * b) * DD + d] + Npart[(size_t)(2 * b + 1) * DD + d];
    float z = Zpart[2 * b] + Zpart[2 * b + 1];
    A[idx] = n / z;
  }
  gsync(cnt, rel, 4);

  // ===== P5: epilogue split-k partials =====
  {
    const int dbase = (bid & 15) * 64;
    const int ks = bid >> 4;  // 0..15
    const int bq = t >> 4;    // 0..31 -> b rows bq*4..bq*4+3
    const int dg = t & 15;    // 0..15 -> d cols dg*4..dg*4+3
    float4 accf[4] = {};
    float4 accm[4] = {};
    // f: 128 k-rows of concat([A, z_rppg]) @ Wf_w
    {
      const float* src = (ks < 8) ? (A + ks * 128) : (z_rppg + (ks - 8) * 128);
      const float* wsrc = Wf_w + (size_t)ks * 128 * DD;
      for (int k0 = 0; k0 < 128; k0 += 32) {
#pragma unroll
        for (int j = 0; j < 8; ++j) {
          int i = t + NTH * j; int bb = i >> 5, c = i & 31;
          sh.e.Cst[c][bb] = src[(size_t)bb * DD + k0 + c];
        }
#pragma unroll
        for (int j = 0; j < 4; ++j) {
          int i = t + NTH * j; int r = i >> 6, c = i & 63;
          sh.e.Wst[r][c] = wsrc[(size_t)(k0 + r) * DD + dbase + c];
        }
        __syncthreads();
#pragma unroll
        for (int kk = 0; kk < 32; ++kk) {
          float4 a4 = *(const float4*)&sh.e.Cst[kk][bq * 4];
          float4 w4 = *(const float4*)&sh.e.Wst[kk][dg * 4];
          outer_acc(accf, a4, w4);
        }
        __syncthreads();
      }
    }
    // m: 64 k-rows of A @ Wm_w
    {
      const float* src = A + ks * 64;
      const float* wsrc = Wm_w + (size_t)ks * 64 * DD;
      for (int k0 = 0; k0 < 64; k0 += 32) {
#pragma unroll
        for (int j = 0; j < 8; ++j) {
          int i = t + NTH * j; int bb = i >> 5, c = i & 31;
          sh.e.Cst[c][bb] = src[(size_t)bb * DD + k0 + c];
        }
#pragma unroll
        for (int j = 0; j < 4; ++j) {
          int i = t + NTH * j; int r = i >> 6, c = i & 63;
          sh.e.Wst[r][c] = wsrc[(size_t)(k0 + r) * DD + dbase + c];
        }
        __syncthreads();
#pragma unroll
        for (int kk = 0; kk < 32; ++kk) {
          float4 a4 = *(const float4*)&sh.e.Cst[kk][bq * 4];
          float4 w4 = *(const float4*)&sh.e.Wst[kk][dg * 4];
          outer_acc(accm, a4, w4);
        }
        __syncthreads();
      }
    }
#pragma unroll
    for (int i = 0; i < 4; ++i) {
      const int b = bq * 4 + i;
      *(float4*)&fpart[(size_t)ks * (BB * DD) + (size_t)b * DD + dbase + dg * 4] = accf[i];
      *(float4*)&mpart[(size_t)ks * (BB * DD) + (size_t)b * DD + dbase + dg * 4] = accm[i];
    }
  }
  gsync(cnt, rel, 5);

  // ===== P6: combine -> h =====
  {
    const int idx = bid * NTH + t;
    const int d = idx & 1023;
    float f = Wf_b[d] + bfp[d];
    float m = Wm_b[d];
#pragma unroll
    for (int k = 0; k < KSE; ++k) {
      f += fpart[(size_t)k * (BB * DD) + idx];
      m += mpart[(size_t)k * (BB * DD) + idx];
    }
    const float g = 1.f / (1.f + __expf(-f));
    const float h = z_rppg[idx] + m * g;
    out[idx] = h > 0.f ? h : 0.f;
  }
}

extern "C" void kernel_launch(void* const* d_in, const int* in_sizes, int n_in,
                              void* d_out, int out_size, void* d_ws, size_t ws_size,
                              hipStream_t stream) {
  const float* z_eeg  = (const float*)d_in[0];
  const float* z_rppg = (const float*)d_in[1];
  const float* Wq     = (const float*)d_in[2];
  const float* Wk     = (const float*)d_in[3];
  const float* Wm_w   = (const float*)d_in[4];
  const float* Wm_b   = (const float*)d_in[5];
  const float* Wf_w   = (const float*)d_in[6];
  const float* Wf_b   = (const float*)d_in[7];
  const float* bfp    = (const float*)d_in[8];
  float* out = (float*)d_out;

  // barrier state (2 ints) at ws start; re-zeroed every call (capturable memset)
  int* cnt = (int*)d_ws;
  int* rel = cnt + 1;
  hipMemsetAsync(d_ws, 0, 16, stream);

  float* base   = (float*)d_ws + 256;               // 1 KB reserved for barrier
  float* Qpart  = base;                             // 4*128*1024
  float* Qkpart = Qpart + (size_t)QS * BB * DD;     // 4*128*1024
  float* Npart  = Qkpart + (size_t)QS * BB * DD;    // 2*128*1024 (one row per bid)
  float* Zpart  = Npart + (size_t)2 * BB * DD;      // 256
  float* A      = Zpart + 2 * BB;                   // 128*1024
  float* fpart  = A + (size_t)BB * DD;              // 16*128*1024
  float* mpart  = fpart + (size_t)KSE * BB * DD;    // 16*128*1024

  k_fused<<<NB, NTH, 0, stream>>>(z_eeg, z_rppg, Wq, Wk, Wm_w, Wm_b, Wf_w, Wf_b,
                                  bfp, out, Qpart, Qkpart, Npart, Zpart, A,
                                  fpart, mpart, cnt, rel);
}